// Round 9
// baseline (504.583 us; speedup 1.0000x reference)
//
#include <hip/hip_runtime.h>

// B=16384, D=1024, H=1024
//   g=r*cos(th), phi=r*sin(th), norm=sqrt(max(1-r^2,0))
//   h_t_c1 = g*h_c1 - phi*h_c2 + norm*(x@w1)
//   h_t_c2 = g*h_c2 + phi*h_c1 + norm*(x@w2)
//   h_t = relu(concat(h_t_c1,h_t_c2))
// Outputs flat fp32: [h_t_c1 (B*H)] [h_t_c2 (B*H)] [h_t (B*2H)]
//
// R9: 128x128 tile, BK=64, *512 threads* (8 waves 2m x 4n), 2-buffer 64 KiB
// LDS -> 2 blocks/CU = 16 waves/CU = 4 waves/SIMD (double R8's TLP).
// Schedule/swizzle/counted-vmcnt identical to R8 (vmcnt(4): 4 loads/stage).

#define Mdim 16384
#define Kdim 1024
#define Hd   1024
#define MH   16777216   // Mdim*Hd

typedef __bf16 bf16x8 __attribute__((ext_vector_type(8)));
typedef float f32x4 __attribute__((ext_vector_type(4)));

__device__ __forceinline__ unsigned short f2bf(float f) {
  union { float f; unsigned int u; } c; c.f = f;
  unsigned int u = c.u;
  u += 0x7fffu + ((u >> 16) & 1u);   // RNE
  return (unsigned short)(u >> 16);
}

__device__ __forceinline__ void gload16(const void* g, void* l) {
  __builtin_amdgcn_global_load_lds(
      (const __attribute__((address_space(1))) void*)g,
      (__attribute__((address_space(3))) void*)l,
      16, 0, 0);
}

// ---- pre-kernel 1: x fp32 -> bf16, plus g/phi table (fused) ----
__global__ __launch_bounds__(256) void convert_gpn_kernel(
    const float* __restrict__ x, unsigned short* __restrict__ xb,
    const float* __restrict__ rp, const float* __restrict__ th,
    float* __restrict__ gphi) {
  const int b = blockIdx.x;
  if (b < 2048) {
    const long n4 = (long)Mdim * Kdim / 4;
    long i = (long)b * 256 + threadIdx.x;
    for (; i < n4; i += 2048L * 256) {
      float4 v = ((const float4*)x)[i];
      ushort4 o;
      o.x = f2bf(v.x); o.y = f2bf(v.y); o.z = f2bf(v.z); o.w = f2bf(v.w);
      ((ushort4*)xb)[i] = o;
    }
  } else {
    const int h = (b - 2048) * 256 + threadIdx.x;
    if (h < Hd) {
      float rv = rp[h], tv = th[h];
      gphi[h]      = rv * cosf(tv);
      gphi[Hd + h] = rv * sinf(tv);
    }
  }
}

// ---- pre-kernel 2: wT[n][k] = norm[h] * w{1,2}[k][h] (bf16), interleaved:
//      n = (h>>7)*256 + half*128 + (h&127) ----
__global__ __launch_bounds__(256) void transpose_w_kernel(
    const float* __restrict__ w1, const float* __restrict__ w2,
    const float* __restrict__ rp, unsigned short* __restrict__ wT) {
  __shared__ unsigned short tile[32][33];
  const int b = blockIdx.x;             // 32 k-tiles x 64 col-tiles
  const int kt = b & 31, ct = b >> 5;
  const int half = ct & 1, h0 = (ct >> 1) * 32;
  const int k0 = kt * 32;
  const int n0 = (h0 >> 7) * 256 + half * 128 + (h0 & 127);
  const float* src = half ? w2 : w1;
  const int r = threadIdx.x >> 5, c = threadIdx.x & 31;
  const float rv = rp[h0 + c];
  const float nm = sqrtf(fmaxf(1.0f - rv * rv, 0.0f));
#pragma unroll
  for (int i = 0; i < 32; i += 8)
    tile[r + i][c] = f2bf(src[(long)(k0 + r + i) * Hd + h0 + c] * nm);
  __syncthreads();
#pragma unroll
  for (int i = 0; i < 32; i += 8)
    wT[(long)(n0 + r + i) * Kdim + k0 + c] = tile[c][r + i];
}

// ---- main GEMM: 2048 blocks x 512 thr; block = 128 m x (64 h x 2 halves) ----
__global__ __launch_bounds__(512, 4) void gemm128_kernel(
    const unsigned short* __restrict__ xb,   // [M][K] bf16
    const unsigned short* __restrict__ wT,   // [N][K] bf16 (norm-scaled, interleaved)
    const float* __restrict__ gphi,          // [2][H]
    const float* __restrict__ hc1,           // [M][H]
    const float* __restrict__ hc2,           // [M][H]
    float* __restrict__ out) {
  extern __shared__ char smem[];             // 65536 B: 2 bufs x (A 16K | B 16K)

  const int tid = threadIdx.x;
  const int lane = tid & 63;
  const int wv = tid >> 6;                   // 0..7
  const int wm = wv >> 2, wn = wv & 3;       // 2m x 4n waves; wave = 64m x 32n out
  const int lr = lane & 15, kq = lane >> 4;
  const int swzl = (lr & 7) << 4;            // read-side XOR swizzle (bits 4-6)

  // T1: XCD swizzle, 2048 blocks -> 256-contiguous g per XCD
  const int g = (blockIdx.x & 7) * 256 + (blockIdx.x >> 3);
  const int tm = g >> 4, hb = g & 15;        // 128 m-tiles x 16 h-tiles
  const int m0 = tm * 128;
  const int nbase = (hb >> 1) * 256 + (hb & 1) * 64;  // wT n for strip row r:
                                                       // nbase + (r>>6)*128 + (r&63)
  const char* xbB = (const char*)xb;
  const char* wTB = (const char*)wT;
  const int r0 = tid >> 3;                                  // 0..63, +64 on 2nd load
  const int swsrc = (((tid & 7) ^ ((tid >> 3) & 7)) << 4);  // pre-swizzled source

  auto stage = [&](int buf, int kt) {
    char* ldA = smem + buf * 32768 + tid * 16;
    char* ldB = ldA + 16384;
#pragma unroll
    for (int i = 0; i < 2; ++i) {
      const int r = r0 + 64 * i;             // r&7 invariant across i
      gload16(xbB + ((size_t)(m0 + r) << 11) + kt * 128 + swsrc, ldA + i * 8192);
      const int n = nbase + ((r >> 6) << 7) + (r & 63);
      gload16(wTB + ((size_t)n << 11) + kt * 128 + swsrc, ldB + i * 8192);
    }
  };

  stage(0, 0);
  stage(1, 1);
  asm volatile("s_waitcnt vmcnt(4)" ::: "memory");   // tile0 landed, tile1 in flight
  __builtin_amdgcn_s_barrier();

  f32x4 acc[4][2] = {};
  bf16x8 a[4][2], bb[2][2];

  for (int t = 0; t < 16; ++t) {
    const char* Ab = smem + (t & 1) * 32768;
    const char* Bb = Ab + 16384;

#pragma unroll
    for (int mi = 0; mi < 4; ++mi)
#pragma unroll
      for (int ks = 0; ks < 2; ++ks)
        a[mi][ks] = *(const bf16x8*)(Ab + (wm * 64 + mi * 16 + lr) * 128 +
                                     ((ks * 64 + kq * 16) ^ swzl));
#pragma unroll
    for (int ni = 0; ni < 2; ++ni)
#pragma unroll
      for (int ks = 0; ks < 2; ++ks)
        bb[ni][ks] = *(const bf16x8*)(Bb + (wn * 32 + ni * 16 + lr) * 128 +
                                      ((ks * 64 + kq * 16) ^ swzl));

    asm volatile("s_waitcnt lgkmcnt(0)" ::: "memory");   // my reads of this buf done
    __builtin_amdgcn_sched_barrier(0);
    __builtin_amdgcn_s_barrier();                        // ALL waves done reading buf
    __builtin_amdgcn_sched_barrier(0);

    stage(t & 1, (t + 2 < 16) ? t + 2 : 15);             // overwrite fully-read buf

    __builtin_amdgcn_s_setprio(1);
#pragma unroll
    for (int ks = 0; ks < 2; ++ks)
#pragma unroll
      for (int mi = 0; mi < 4; ++mi)
#pragma unroll
        for (int ni = 0; ni < 2; ++ni)
          acc[mi][ni] = __builtin_amdgcn_mfma_f32_16x16x32_bf16(
              a[mi][ks], bb[ni][ks], acc[mi][ni], 0, 0, 0);
    __builtin_amdgcn_s_setprio(0);

    asm volatile("s_waitcnt vmcnt(4)" ::: "memory");     // next tile landed; 4 in flight
    __builtin_amdgcn_sched_barrier(0);
    __builtin_amdgcn_s_barrier();
    __builtin_amdgcn_sched_barrier(0);
  }
  asm volatile("s_waitcnt vmcnt(0)" ::: "memory");       // drain dup stages before exit

  // ---- fused epilogue ----
  // wave's strip rows s = wn*32 + ni*16 + lr; halfsel = s>>6 = wn>>1;
  // h = hb*64 + (s&63) = hb*64 + (wn&1)*32 + ni*16 + lr
  const int crow = kq * 4;
  const int halfsel = wn >> 1;
  float* outc = out + (size_t)halfsel * MH;
  float* o2b  = out + 2 * (size_t)MH + (size_t)halfsel * Hd;

  float gg[2], pp[2];
  int hx[2];
#pragma unroll
  for (int ni = 0; ni < 2; ++ni) {
    const int h = hb * 64 + (wn & 1) * 32 + ni * 16 + lr;
    hx[ni] = h;
    gg[ni] = gphi[h];
    pp[ni] = gphi[Hd + h];
  }

#pragma unroll
  for (int mi = 0; mi < 4; ++mi) {
#pragma unroll
    for (int j = 0; j < 4; ++j) {
      const size_t row = (size_t)m0 + wm * 64 + mi * 16 + crow + j;
      const float* p1 = hc1 + row * Hd;
      const float* p2 = hc2 + row * Hd;
      float* oc = outc + row * Hd;
      float* o2 = o2b + row * 2048;
#pragma unroll
      for (int ni = 0; ni < 2; ++ni) {
        const int h = hx[ni];
        const float h1 = p1[h];
        const float h2 = p2[h];
        const float wx = acc[mi][ni][j];     // norm folded into wT
        const float v = halfsel ? fmaf(gg[ni], h2, fmaf(pp[ni], h1, wx))
                                : fmaf(gg[ni], h1, fmaf(-pp[ni], h2, wx));
        oc[h] = v;
        o2[h] = fmaxf(v, 0.0f);
      }
    }
  }
}

extern "C" void kernel_launch(void* const* d_in, const int* in_sizes, int n_in,
                              void* d_out, int out_size, void* d_ws, size_t ws_size,
                              hipStream_t stream) {
  const float* hc1 = (const float*)d_in[0];
  const float* hc2 = (const float*)d_in[1];
  const float* x   = (const float*)d_in[2];
  const float* rp  = (const float*)d_in[3];
  const float* th  = (const float*)d_in[4];
  const float* w1  = (const float*)d_in[5];
  const float* w2  = (const float*)d_in[6];
  float* out = (float*)d_out;

  char* ws = (char*)d_ws;
  unsigned short* xb = (unsigned short*)ws;                                   // 32 MB
  unsigned short* wT = (unsigned short*)(ws + (size_t)Mdim * Kdim * 2);       // 4 MB
  float* gphi = (float*)(ws + (size_t)Mdim * Kdim * 2 + (size_t)2048 * Kdim * 2);

  (void)hipFuncSetAttribute((const void*)gemm128_kernel,
                            hipFuncAttributeMaxDynamicSharedMemorySize, 65536);

  convert_gpn_kernel<<<2052, 256, 0, stream>>>(x, xb, rp, th, gphi);
  transpose_w_kernel<<<2048, 256, 0, stream>>>(w1, w2, rp, wT);
  gemm128_kernel<<<2048, 512, 65536, stream>>>(xb, wT, gphi, hc1, hc2, out);
}